// Round 1
// baseline (383.415 us; speedup 1.0000x reference)
//
#include <hip/hip_runtime.h>
#include <hip/hip_fp16.h>

// CapsuleLayer dynamic routing, fully fused.
// B=256, IN_CAPS=1152, IN_DIM=8, NUM_CAPS=10, DIM_VEC=16, NUM_ROUTING=3.
//
// Design (round 1): one block per batch element b (grid=256, 1 block/CU).
// logits[1152][10] persist in LDS across the 3 routing rounds; hat[i,j,:] is
// recomputed each round from W (streamed from L2) and used for BOTH the
// agreement update and the coupling-weighted sum in a single pass, so hat is
// never materialized. W is converted to fp16 once per launch (prep kernel) to
// halve the dominant per-block W stream (5.9 MB -> 2.95 MB per round).

#define NB 256
#define IC 1152
#define IE 8
#define NC 10
#define DV 16
#define NW (IC * NC * IE * DV)  // 1,474,560 W elements
#define TM 640                  // threads/block = 64 row-groups x 10 j
#define RPS (TM / NC)           // 64 rows per step
#define NSTEP (IC / RPS)        // 18 steps

__global__ void w2h_kernel(const float* __restrict__ W, __half* __restrict__ Wh) {
    const int n4 = NW / 4;
    for (int k = blockIdx.x * blockDim.x + threadIdx.x; k < n4;
         k += gridDim.x * blockDim.x) {
        float4 w = ((const float4*)W)[k];
        __half2* o = (__half2*)Wh + 2 * (size_t)k;
        o[0] = __floats2half2_rn(w.x, w.y);
        o[1] = __floats2half2_rn(w.z, w.w);
    }
}

template <bool USE_H>
__global__ __launch_bounds__(TM) void caps_kernel(
    const float* __restrict__ X,    // [B, IC, IE] fp32
    const void* __restrict__ Wv,    // [IC, NC, IE, DV] fp16 (or fp32 fallback)
    const float* __restrict__ bias, // [IC*NC] fp32
    float* __restrict__ out)        // [B, NC, DV] fp32
{
    __shared__ float logits[IC * NC];  // 46,080 B, persists across rounds
    __shared__ float v_lds[NC * DV];   // squashed output caps of prev round
    __shared__ float s_glob[NC * DV];  // block-wide s accumulator

    const int b = blockIdx.x;
    const int tid = threadIdx.x;
    const int g = tid / NC;       // row group 0..63
    const int j = tid - g * NC;   // output capsule 0..9
    const float* xb = X + (size_t)b * IC * IE;

    // logits start at bias (broadcast over b)
    for (int k = tid; k < IC * NC; k += TM) logits[k] = bias[k];
    __syncthreads();

    for (int r = 0; r < 3; ++r) {
        if (tid < NC * DV) s_glob[tid] = 0.f;
        __syncthreads();

        float s_acc[DV];
#pragma unroll
        for (int d = 0; d < DV; ++d) s_acc[d] = 0.f;

        for (int s = 0; s < NSTEP; ++s) {
            const int i = s * RPS + g;

            // inputs row (L1/L2 resident, 10-lane broadcast)
            const float4* xr = (const float4*)(xb + (size_t)i * IE);
            float4 x0 = xr[0], x1 = xr[1];
            float in_e[IE] = {x0.x, x0.y, x0.z, x0.w, x1.x, x1.y, x1.z, x1.w};

            // hat[i,j,:] = sum_e in[i,e] * W[i,j,e,:]
            float hat[DV];
#pragma unroll
            for (int d = 0; d < DV; ++d) hat[d] = 0.f;

            if (USE_H) {
                const float4* wp =
                    (const float4*)((const __half*)Wv + (size_t)(i * NC + j) * IE * DV);
#pragma unroll
                for (int e = 0; e < IE; ++e) {
                    float4 wa = wp[2 * e];      // halves d=0..7
                    float4 wb = wp[2 * e + 1];  // halves d=8..15
                    float ie = in_e[e];
                    const __half2* ha = (const __half2*)&wa;
                    const __half2* hb = (const __half2*)&wb;
#pragma unroll
                    for (int q = 0; q < 4; ++q) {
                        float2 fa = __half22float2(ha[q]);
                        float2 fb = __half22float2(hb[q]);
                        hat[2 * q]         = fmaf(ie, fa.x, hat[2 * q]);
                        hat[2 * q + 1]     = fmaf(ie, fa.y, hat[2 * q + 1]);
                        hat[8 + 2 * q]     = fmaf(ie, fb.x, hat[8 + 2 * q]);
                        hat[8 + 2 * q + 1] = fmaf(ie, fb.y, hat[8 + 2 * q + 1]);
                    }
                }
            } else {
                const float4* wp =
                    (const float4*)((const float*)Wv + (size_t)(i * NC + j) * IE * DV);
#pragma unroll
                for (int e = 0; e < IE; ++e) {
                    float ie = in_e[e];
#pragma unroll
                    for (int q = 0; q < 4; ++q) {
                        float4 w = wp[4 * e + q];
                        hat[4 * q]     = fmaf(ie, w.x, hat[4 * q]);
                        hat[4 * q + 1] = fmaf(ie, w.y, hat[4 * q + 1]);
                        hat[4 * q + 2] = fmaf(ie, w.z, hat[4 * q + 2]);
                        hat[4 * q + 3] = fmaf(ie, w.w, hat[4 * q + 3]);
                    }
                }
            }

            if (r > 0) {
                // agreement: logits[i,j] += <hat[i,j,:], v[j,:]>
                float a = 0.f;
#pragma unroll
                for (int d = 0; d < DV; ++d) a = fmaf(hat[d], v_lds[j * DV + d], a);
                logits[i * NC + j] += a;
                __syncthreads();  // order writes vs row-softmax reads (uniform branch)
            }

            // softmax over j for row i (redundant across the 10 j-lanes, tiny)
            const float* lrow = &logits[i * NC];
            float mx = lrow[0];
#pragma unroll
            for (int jj = 1; jj < NC; ++jj) mx = fmaxf(mx, lrow[jj]);
            float Z = 0.f;
#pragma unroll
            for (int jj = 0; jj < NC; ++jj) Z += __expf(lrow[jj] - mx);
            float c = __expf(lrow[j] - mx) / Z;

#pragma unroll
            for (int d = 0; d < DV; ++d) s_acc[d] = fmaf(c, hat[d], s_acc[d]);
        }

        // merge per-thread partial s into block s (64-way per address, once/round)
#pragma unroll
        for (int d = 0; d < DV; ++d) atomicAdd(&s_glob[j * DV + d], s_acc[d]);
        __syncthreads();

        // squash: v = |s|^2/(1+|s|^2)/|s| * s  (threads 0..159 own (j,d))
        if (tid < NC * DV) {
            float sv = s_glob[tid];
            float s2 = sv * sv;
#pragma unroll
            for (int mk = 8; mk >= 1; mk >>= 1) s2 += __shfl_xor(s2, mk, 16);
            float scale = sqrtf(s2) / (1.0f + s2);
            float vv = scale * sv;
            if (r < 2) v_lds[tid] = vv;
            else out[(size_t)b * NC * DV + tid] = vv;
        }
        __syncthreads();
    }
}

extern "C" void kernel_launch(void* const* d_in, const int* in_sizes, int n_in,
                              void* d_out, int out_size, void* d_ws, size_t ws_size,
                              hipStream_t stream) {
    const float* X = (const float*)d_in[0];     // [256,1152,8]
    const float* W = (const float*)d_in[1];     // [1152,10,8,16]
    const float* bias = (const float*)d_in[2];  // [1,1152,10]
    float* out = (float*)d_out;

    if (ws_size >= (size_t)NW * sizeof(__half)) {
        __half* Wh = (__half*)d_ws;
        w2h_kernel<<<dim3(720), dim3(256), 0, stream>>>(W, Wh);
        caps_kernel<true><<<dim3(NB), dim3(TM), 0, stream>>>(X, (const void*)Wh, bias, out);
    } else {
        // workspace too small for fp16 W: read fp32 W directly (2x L2 traffic)
        caps_kernel<false><<<dim3(NB), dim3(TM), 0, stream>>>(X, (const void*)W, bias, out);
    }
}